// Round 1
// baseline (37.336 us; speedup 1.0000x reference)
//
#include <hip/hip_runtime.h>

// QuantizedBn2d: per-sample-cluster int32 affine + gemmlowp fixed-point requantize.
// B=32, C=256, H=W=56. Elementwise, memory-bound (~206 MB traffic).

#define CCH 256
#define HW  3136   // 56*56
#define HW4 784    // HW/4 (float4 units)

__global__ __launch_bounds__(256) void qbn_kernel(
    const float* __restrict__ x,
    const int*   __restrict__ weight,
    const int*   __restrict__ bias,
    const int*   __restrict__ z1,
    const int*   __restrict__ z2,
    const int*   __restrict__ z3,
    const int*   __restrict__ M0,
    const int*   __restrict__ shiftp,
    const int*   __restrict__ bcluster,
    float*       __restrict__ out)
{
    const int slice = blockIdx.x;        // slice = b*C + c
    const int b = slice >> 8;            // / 256
    const int c = slice & 255;

    const int cl = bcluster[b];
    const int w  = weight[cl * CCH + c];
    const int bi = bias[cl * CCH + c];
    const int Z1 = z1[cl], Z2 = z2[cl], Z3 = z3[cl];
    const int m0 = M0[cl];
    const int sh = shiftp[cl];
    const int s_neg = sh < 0 ? -sh : 0;
    const int s_pos = sh > 0 ?  sh : 0;

    const int A  = w - Z2;                       // xi * A + Bc == subsum (int32-exact)
    const int Bc = bi - w * Z1 + Z1 * Z2;
    const long long mask = (1LL << s_pos) - 1;
    const long long half = mask >> 1;

    const float4* xin  = reinterpret_cast<const float4*>(x   + (size_t)slice * HW);
    float4*       xout = reinterpret_cast<float4*>      (out + (size_t)slice * HW);

    for (int i = threadIdx.x; i < HW4; i += 256) {
        float4 v = xin[i];
        float4 r;
        float* vf = &v.x;
        float* rf = &r.x;
        #pragma unroll
        for (int j = 0; j < 4; ++j) {
            int xi = (int)vf[j];                                   // exact: x holds 0..255
            long long subsum = (long long)(xi * A + Bc) << s_neg;  // s_neg <= 2
            long long ab     = subsum * (long long)m0;
            long long nudge  = ab >= 0 ? (1LL << 30) : (1LL - (1LL << 30));
            long long mul    = (ab + nudge) >> 31;                 // multiply_M
            // RoundingDivideByPOT(mul, s_pos)
            long long rem = mul & mask;
            long long thr = half + (mul < 0 ? 1 : 0);
            int total = (int)((mul >> s_pos) + (rem > thr ? 1 : 0)) + Z3;
            total = total < -128 ? -128 : (total > 127 ? 127 : total);
            rf[j] = (float)total;
        }
        xout[i] = r;
    }
}

extern "C" void kernel_launch(void* const* d_in, const int* in_sizes, int n_in,
                              void* d_out, int out_size, void* d_ws, size_t ws_size,
                              hipStream_t stream) {
    const float* x      = (const float*)d_in[0];
    const int*   weight = (const int*)  d_in[1];
    const int*   bias   = (const int*)  d_in[2];
    const int*   z1     = (const int*)  d_in[3];
    const int*   z2     = (const int*)  d_in[4];
    const int*   z3     = (const int*)  d_in[5];
    const int*   M0     = (const int*)  d_in[6];
    const int*   shiftp = (const int*)  d_in[7];
    const int*   bc     = (const int*)  d_in[8];
    float*       out    = (float*)d_out;

    const int B = in_sizes[8];           // 32
    const int nslices = B * CCH;         // 8192
    hipLaunchKernelGGL(qbn_kernel, dim3(nslices), dim3(256), 0, stream,
                       x, weight, bias, z1, z2, z3, M0, shiftp, bc, out);
}

// Round 3
// 35.644 us; speedup vs baseline: 1.0475x; 1.0475x over previous
//
#include <hip/hip_runtime.h>

// QuantizedBn2d: per-sample-cluster int32 affine + gemmlowp fixed-point requantize.
// B=32, C=256, H=W=56. Elementwise, memory-bound (~150 MB steady-state HBM traffic).
// R3: R2 with native ext_vector float4 so __builtin_nontemporal_store compiles.

#define CCH 256
#define HW  3136   // 56*56
#define HW4 784    // HW/4 (float4 units); 784 = 3*256 + 16

typedef float v4f __attribute__((ext_vector_type(4)));

__device__ __forceinline__ v4f proc4(v4f v, int A, int Bc, int s_neg,
                                     int s_pos, int m0, int mask, int half,
                                     int Z3) {
    v4f r;
    #pragma unroll
    for (int j = 0; j < 4; ++j) {
        int xi = (int)v[j];                                   // exact: x holds 0..255
        int sub = (xi * A + Bc) << s_neg;                     // |sub| < 2^20
        long long ab = (long long)sub * (long long)m0;        // < 2^51
        long long nudge = ab >= 0 ? (1LL << 30) : (1LL - (1LL << 30));
        int mul = (int)((ab + nudge) >> 31);                  // |mul| <= 2^21 -> int32
        // RoundingDivideByPOT in 32-bit
        int rem = mul & mask;
        int thr = half + (mul < 0 ? 1 : 0);
        int tot = (mul >> s_pos) + (rem > thr ? 1 : 0) + Z3;
        tot = tot < -128 ? -128 : (tot > 127 ? 127 : tot);    // v_med3_i32
        r[j] = (float)tot;
    }
    return r;
}

__global__ __launch_bounds__(256) void qbn_kernel(
    const float* __restrict__ x,
    const int*   __restrict__ weight,
    const int*   __restrict__ bias,
    const int*   __restrict__ z1,
    const int*   __restrict__ z2,
    const int*   __restrict__ z3,
    const int*   __restrict__ M0,
    const int*   __restrict__ shiftp,
    const int*   __restrict__ bcluster,
    float*       __restrict__ out)
{
    const int slice = blockIdx.x;        // slice = b*C + c
    const int b = slice >> 8;            // / 256
    const int c = slice & 255;

    const int cl = bcluster[b];
    const int w  = weight[cl * CCH + c];
    const int bi = bias[cl * CCH + c];
    const int Z1 = z1[cl], Z2 = z2[cl], Z3 = z3[cl];
    const int m0 = M0[cl];
    const int sh = shiftp[cl];
    const int s_neg = sh < 0 ? -sh : 0;
    const int s_pos = sh > 0 ?  sh : 0;

    const int A    = w - Z2;                     // xi*A + Bc == subsum (int32-exact)
    const int Bc   = bi - w * Z1 + Z1 * Z2;
    const int mask = (1 << s_pos) - 1;           // s_pos <= 11
    const int half = mask >> 1;

    const v4f* xin  = reinterpret_cast<const v4f*>(x   + (size_t)slice * HW);
    v4f*       xout = reinterpret_cast<v4f*>      (out + (size_t)slice * HW);

    const int t = threadIdx.x;
    // all three loads independent & in flight before any compute
    v4f v0 = xin[t];
    v4f v1 = xin[t + 256];
    v4f v2 = xin[t + 512];
    v4f vt;
    const bool tail = t < (HW4 - 768);           // 16 threads
    if (tail) vt = xin[t + 768];

    v4f r0 = proc4(v0, A, Bc, s_neg, s_pos, m0, mask, half, Z3);
    v4f r1 = proc4(v1, A, Bc, s_neg, s_pos, m0, mask, half, Z3);
    v4f r2 = proc4(v2, A, Bc, s_neg, s_pos, m0, mask, half, Z3);

    __builtin_nontemporal_store(r0, &xout[t]);
    __builtin_nontemporal_store(r1, &xout[t + 256]);
    __builtin_nontemporal_store(r2, &xout[t + 512]);
    if (tail) {
        v4f rt = proc4(vt, A, Bc, s_neg, s_pos, m0, mask, half, Z3);
        __builtin_nontemporal_store(rt, &xout[t + 768]);
    }
}

extern "C" void kernel_launch(void* const* d_in, const int* in_sizes, int n_in,
                              void* d_out, int out_size, void* d_ws, size_t ws_size,
                              hipStream_t stream) {
    const float* x      = (const float*)d_in[0];
    const int*   weight = (const int*)  d_in[1];
    const int*   bias   = (const int*)  d_in[2];
    const int*   z1     = (const int*)  d_in[3];
    const int*   z2     = (const int*)  d_in[4];
    const int*   z3     = (const int*)  d_in[5];
    const int*   M0     = (const int*)  d_in[6];
    const int*   shiftp = (const int*)  d_in[7];
    const int*   bc     = (const int*)  d_in[8];
    float*       out    = (float*)d_out;

    const int B = in_sizes[8];           // 32
    const int nslices = B * CCH;         // 8192
    hipLaunchKernelGGL(qbn_kernel, dim3(nslices), dim3(256), 0, stream,
                       x, weight, bias, z1, z2, z3, M0, shiftp, bc, out);
}